// Round 3
// baseline (1449.705 us; speedup 1.0000x reference)
//
#include <hip/hip_runtime.h>
#include <hip/hip_bf16.h>

// GraphConvLayer B=4,N=128,D=512,H=8.
// Input dtype (bf16|fp32) runtime-detected -> flag in ws; OUTPUT dtype follows
// input dtype (f==1 -> fp32 out, f==0 -> bf16 out).
// `u` (64MB bf16) lives inside the outE region of d_out, block-strided: k6
// block bm owns outE rows [bm*64, bm*64+64); its u rows occupy the first
// 65536 bytes of that block's own outE byte range -> in-place transform is
// race-free for both output dtypes. ws use ~12.3MB.

typedef __bf16  bf16x8 __attribute__((ext_vector_type(8)));
typedef float   f32x4  __attribute__((ext_vector_type(4)));
typedef __hip_bfloat16 bfloat;

#define AS1 __attribute__((address_space(1)))
#define AS3 __attribute__((address_space(3)))

__device__ __forceinline__ void g2l16(const void* g, void* l) {
  __builtin_amdgcn_global_load_lds((AS1 void*)g, (AS3 void*)l, 16, 0, 0);
}

__device__ __forceinline__ float ldf(const void* p, size_t i, int f) {
  return f ? ((const float*)p)[i] : __bfloat162float(((const bfloat*)p)[i]);
}
__device__ __forceinline__ void stf(void* p, size_t i, float v, int f) {
  if (f) ((float*)p)[i] = v;
  else   ((bfloat*)p)[i] = __float2bfloat16(v);
}

__global__ __launch_bounds__(256) void detect_dtype(const unsigned short* nu, int* flag) {
  __shared__ int bad;
  if (threadIdx.x == 0) bad = 0;
  __syncthreads();
  int local = 0;
  for (int i = threadIdx.x; i < 4096; i += 256) {
    int ex = (nu[i] >> 7) & 0xFF;   // bf16-view exponent; >=0xC0 (|x|>=2^65) impossible for data
    if (ex >= 0xC0) local = 1;
  }
  if (local) atomicOr(&bad, 1);
  __syncthreads();
  if (threadIdx.x == 0) *flag = bad;
}

__global__ __launch_bounds__(256) void cvt_node(const void* node, const int* flag, float* nodeF) {
  const int f = *flag;
  const int i = blockIdx.x * 256 + threadIdx.x;  // grid 1024
  nodeF[i] = ldf(node, i, f);
}

__global__ __launch_bounds__(256) void transpose3(const void* We1, const void* Wu1,
                                                  const void* Wu2, const int* flag,
                                                  bfloat* WtA, bfloat* WtB, bfloat* WtC) {
  const int f = *flag;
  int idx = blockIdx.x * 256 + threadIdx.x;  // 3*2^18
  int m = idx >> 18;
  int r = idx & 262143;
  int n = r >> 9, k = r & 511;
  size_t si = (size_t)k * 512 + n;
  float v;
  bfloat* dst;
  if (m == 0)      { v = ldf(We1, 524288 + si, f); dst = WtA; }
  else if (m == 1) { v = ldf(Wu1, 524288 + si, f); dst = WtB; }
  else             { v = ldf(Wu2, si, f);          dst = WtC; }
  dst[(size_t)n * 512 + k] = __float2bfloat16(v);
}

// A fp32 (ws), W dual-dtype with element offset woff, optional bias
__global__ __launch_bounds__(256) void small_gemm(const float* A, const void* W, size_t woff,
                                                  const void* bias, const int* flag,
                                                  float* out) {
  const int f = *flag;
  __shared__ float sA[4][512];
  const int t = threadIdx.x;
  const int r0 = blockIdx.x * 4;
  for (int idx = t; idx < 2048; idx += 256)
    sA[idx >> 9][idx & 511] = A[(size_t)(r0 + (idx >> 9)) * 512 + (idx & 511)];
  __syncthreads();
  float acc0[4] = {0.f, 0.f, 0.f, 0.f}, acc1[4] = {0.f, 0.f, 0.f, 0.f};
#pragma unroll 4
  for (int k = 0; k < 512; ++k) {
    float w0 = ldf(W, woff + (size_t)k * 512 + t, f);
    float w1 = ldf(W, woff + (size_t)k * 512 + t + 256, f);
#pragma unroll
    for (int r = 0; r < 4; ++r) {
      acc0[r] += sA[r][k] * w0;
      acc1[r] += sA[r][k] * w1;
    }
  }
  float b0 = bias ? ldf(bias, t, f) : 0.f;
  float b1 = bias ? ldf(bias, t + 256, f) : 0.f;
#pragma unroll
  for (int r = 0; r < 4; ++r) {
    out[(size_t)(r0 + r) * 512 + t] = acc0[r] + b0;
    out[(size_t)(r0 + r) * 512 + t + 256] = acc1[r] + b1;
  }
}

__global__ __launch_bounds__(256) void k3_edge_mlp(const void* E, const bfloat* WtA,
                                                   const bfloat* WtB, const float* P1,
                                                   const float* Q1, const float* P2,
                                                   const float* Q2, const void* We2,
                                                   const int* flag, float* logits, void* dout) {
  const int f = *flag;
  __shared__ __align__(16) char smem[16384];
  char* sA = smem;
  char* sB = smem + 8192;
  f32x4 acc[4][4];
#pragma unroll
  for (int mi = 0; mi < 4; ++mi)
#pragma unroll
    for (int ni = 0; ni < 4; ++ni) acc[mi][ni] = (f32x4){0.f, 0.f, 0.f, 0.f};

  const int bm = blockIdx.x;      // 0..511 == b*128 + i
  const int bn = blockIdx.y;      // 0..7 : <4 attn path, >=4 u path
  const bool attn = bn < 4;
  const size_t Abase = (size_t)bm * 65536;
  const bfloat* Bg = attn ? WtA + (size_t)bn * 65536 : WtB + (size_t)(bn - 4) * 65536;
  const bfloat* Eb = (const bfloat*)E;
  const float* Ef = (const float*)E;

  const int t = threadIdx.x;
  const int lane = t & 63;
  const int wave = t >> 6;
  const int wrow = wave >> 1, wcol = wave & 1;
  const int l15 = lane & 15;
  const int q = lane >> 4;

  for (int kt = 0; kt < 16; ++kt) {
    __syncthreads();
    const int k0 = kt * 32;
#pragma unroll
    for (int c = 0; c < 2; ++c) {
      const int idx = c * 256 + t;
      const int row = idx >> 2, seg = idx & 3;
      g2l16(Bg + (size_t)row * 512 + k0 + seg * 8, sB + (c * 256 + wave * 64) * 16);
    }
    if (f == 0) {
#pragma unroll
      for (int c = 0; c < 2; ++c) {
        const int idx = c * 256 + t;
        const int row = idx >> 2, seg = idx & 3;
        g2l16(Eb + Abase + (size_t)row * 512 + k0 + seg * 8, sA + (c * 256 + wave * 64) * 16);
      }
    } else {
#pragma unroll
      for (int c = 0; c < 2; ++c) {
        const int idx = c * 256 + t;
        const int row = idx >> 2, seg = idx & 3;
        const float* src = Ef + Abase + (size_t)row * 512 + k0 + seg * 8;
        f32x4 lo = *(const f32x4*)src;
        f32x4 hi = *(const f32x4*)(src + 4);
        bf16x8 v;
        v[0] = (__bf16)lo[0]; v[1] = (__bf16)lo[1]; v[2] = (__bf16)lo[2]; v[3] = (__bf16)lo[3];
        v[4] = (__bf16)hi[0]; v[5] = (__bf16)hi[1]; v[6] = (__bf16)hi[2]; v[7] = (__bf16)hi[3];
        *(bf16x8*)(sA + idx * 16) = v;
      }
    }
    __syncthreads();
    bf16x8 afr[4], bfr[4];
#pragma unroll
    for (int mi = 0; mi < 4; ++mi)
      afr[mi] = *(const bf16x8*)(sA + ((wrow * 64 + mi * 16 + l15) * 32 + q * 8) * 2);
#pragma unroll
    for (int ni = 0; ni < 4; ++ni)
      bfr[ni] = *(const bf16x8*)(sB + ((wcol * 64 + ni * 16 + l15) * 32 + q * 8) * 2);
#pragma unroll
    for (int mi = 0; mi < 4; ++mi)
#pragma unroll
      for (int ni = 0; ni < 4; ++ni)
        acc[mi][ni] = __builtin_amdgcn_mfma_f32_16x16x32_bf16(afr[mi], bfr[ni], acc[mi][ni], 0, 0, 0);
  }

  const int b = bm >> 7;
  const int colbase = (attn ? bn : (bn - 4)) * 128 + wcol * 64;
  const float* P = attn ? P1 : P2;
  const float* Qm = attn ? Q1 : Q2;

  if (!attn) {
    // u destination: block-strided inside outE region of d_out
    char* ub = (char*)dout + (f ? 1048576 : 524288);
    const size_t blkstride = f ? 131072 : 65536;
#pragma unroll
    for (int mi = 0; mi < 4; ++mi)
#pragma unroll
      for (int rr = 0; rr < 4; ++rr) {
        const int j = wrow * 64 + mi * 16 + q * 4 + rr;
        const size_t m = (size_t)bm * 128 + j;      // global edge row
        bfloat* urow = (bfloat*)(ub + (m >> 6) * blkstride) + (m & 63) * 512;
#pragma unroll
        for (int ni = 0; ni < 4; ++ni) {
          const int c = colbase + ni * 16 + l15;
          float x = acc[mi][ni][rr] + P[(size_t)bm * 512 + c] + Qm[((size_t)b * 128 + j) * 512 + c];
          float g = 0.5f * x * (1.0f + erff(x * 0.70710678118654752f));
          urow[c] = __float2bfloat16(g);
        }
      }
  } else {
    float w2[4][8];
#pragma unroll
    for (int ni = 0; ni < 4; ++ni) {
      const int c = colbase + ni * 16 + l15;
#pragma unroll
      for (int hh = 0; hh < 8; ++hh) w2[ni][hh] = ldf(We2, (size_t)c * 8 + hh, f);
    }
#pragma unroll
    for (int mi = 0; mi < 4; ++mi)
#pragma unroll
      for (int rr = 0; rr < 4; ++rr) {
        const int j = wrow * 64 + mi * 16 + q * 4 + rr;
        float e[4];
#pragma unroll
        for (int ni = 0; ni < 4; ++ni) {
          const int c = colbase + ni * 16 + l15;
          float x = acc[mi][ni][rr] + P[(size_t)bm * 512 + c] + Qm[((size_t)b * 128 + j) * 512 + c];
          e[ni] = (x >= 0.f) ? x : 0.2f * x;
        }
        float part[8];
#pragma unroll
        for (int hh = 0; hh < 8; ++hh) {
          float s = e[0] * w2[0][hh] + e[1] * w2[1][hh] + e[2] * w2[2][hh] + e[3] * w2[3][hh];
          s += __shfl_xor(s, 1);
          s += __shfl_xor(s, 2);
          s += __shfl_xor(s, 4);
          s += __shfl_xor(s, 8);
          part[hh] = s;
        }
        if (l15 == 0) {
          float* lp = logits + ((size_t)bm * 128 + j) * 8;
#pragma unroll
          for (int hh = 0; hh < 8; ++hh) atomicAdd(lp + hh, part[hh]);
        }
      }
  }
}

__global__ __launch_bounds__(512) void k6_edge_out(const bfloat* WtC, const void* Wu2b,
                                                   const void* E, const int* flag, void* dout) {
  const int f = *flag;
  __shared__ __align__(16) char smem[36864];
  char* sA = smem;          // 64 rows x 64B
  char* sB = smem + 4096;   // 512 rows x 64B
  f32x4 acc[2][8];
#pragma unroll
  for (int mi = 0; mi < 2; ++mi)
#pragma unroll
    for (int ni = 0; ni < 8; ++ni) acc[mi][ni] = (f32x4){0.f, 0.f, 0.f, 0.f};

  const int bm = blockIdx.x;  // 0..1023, owns outE rows [bm*64, bm*64+64)
  const int t = threadIdx.x;  // 8 waves
  const int lane = t & 63;
  const int wave = t >> 6;
  const int wm = wave >> 2, wn = wave & 3;
  const int l15 = lane & 15;
  const int q = lane >> 4;
  const size_t r0 = (size_t)bm * 64;
  // this block's u rows (bf16), at the start of its own outE byte range
  const bfloat* ua = (const bfloat*)((const char*)dout + (f ? 1048576 : 524288) +
                                     (size_t)bm * (f ? 131072 : 65536));

  for (int kt = 0; kt < 16; ++kt) {
    __syncthreads();
    const int k0 = kt * 32;
    if (t < 256) {
      const int row = t >> 2, seg = t & 3;   // row 0..63 within block
      g2l16(ua + (size_t)row * 512 + k0 + seg * 8, sA + wave * 64 * 16);
    }
#pragma unroll
    for (int c = 0; c < 4; ++c) {
      const int idx = c * 512 + t;
      const int row = idx >> 2, seg = idx & 3;
      g2l16(WtC + (size_t)row * 512 + k0 + seg * 8, sB + (c * 512 + wave * 64) * 16);
    }
    __syncthreads();
    bf16x8 afr[2], bfr[8];
#pragma unroll
    for (int mi = 0; mi < 2; ++mi)
      afr[mi] = *(const bf16x8*)(sA + ((wm * 32 + mi * 16 + l15) * 32 + q * 8) * 2);
#pragma unroll
    for (int ni = 0; ni < 8; ++ni)
      bfr[ni] = *(const bf16x8*)(sB + ((wn * 128 + ni * 16 + l15) * 32 + q * 8) * 2);
#pragma unroll
    for (int mi = 0; mi < 2; ++mi)
#pragma unroll
      for (int ni = 0; ni < 8; ++ni)
        acc[mi][ni] = __builtin_amdgcn_mfma_f32_16x16x32_bf16(afr[mi], bfr[ni], acc[mi][ni], 0, 0, 0);
  }
  // all u reads drained at the loop's final barrier; safe to overwrite own rows
#pragma unroll
  for (int mi = 0; mi < 2; ++mi)
#pragma unroll
    for (int rr = 0; rr < 4; ++rr) {
      const int j = wm * 32 + mi * 16 + q * 4 + rr;
      const size_t row = r0 + j;
#pragma unroll
      for (int ni = 0; ni < 8; ++ni) {
        const int c = wn * 128 + ni * 16 + l15;
        float v = acc[mi][ni][rr] + ldf(Wu2b, c, f) + ldf(E, row * 512 + c, f);
        stf(dout, 262144 + row * 512 + c, v, f);
      }
    }
}

__global__ __launch_bounds__(128) void softmax_mean(const float* logits, const void* adj,
                                                    const int* flag, float* amean) {
  const int f = *flag;
  const int bi = blockIdx.x;
  const int j = threadIdx.x;
  __shared__ float red[128];
  float macc = 0.f;
  for (int hh = 0; hh < 8; ++hh) {
    float x = logits[((size_t)bi * 128 + j) * 8 + hh];
    red[j] = x;
    __syncthreads();
    for (int s = 64; s > 0; s >>= 1) {
      if (j < s) red[j] = fmaxf(red[j], red[j + s]);
      __syncthreads();
    }
    float mx = red[0];
    __syncthreads();
    float ex = expf(x - mx);
    red[j] = ex;
    __syncthreads();
    for (int s = 64; s > 0; s >>= 1) {
      if (j < s) red[j] += red[j + s];
      __syncthreads();
    }
    float sum = red[0];
    __syncthreads();
    macc += ex / sum;
  }
  amean[(size_t)bi * 128 + j] = macc * 0.125f * ldf(adj, (size_t)bi * 128 + j, f);
}

__global__ __launch_bounds__(256) void aggregate(const float* amean, const float* msg,
                                                 float* agg) {
  const int bi = blockIdx.x;
  const int b = bi >> 7;
  const int t = threadIdx.x;
  __shared__ float am[128];
  if (t < 128) am[t] = amean[(size_t)bi * 128 + t];
  __syncthreads();
  float a0 = 0.f, a1 = 0.f;
#pragma unroll 4
  for (int jj = 0; jj < 128; ++jj) {
    const float* mr = msg + ((size_t)b * 128 + jj) * 512;
    a0 += am[jj] * mr[t];
    a1 += am[jj] * mr[t + 256];
  }
  agg[(size_t)bi * 512 + t] = a0;
  agg[(size_t)bi * 512 + t + 256] = a1;
}

__global__ __launch_bounds__(256) void node_out(const float* agg, const void* Wo,
                                                const void* Wob, const float* nodeF,
                                                const void* lng, const void* lnb,
                                                const int* flag, void* dout) {
  const int f = *flag;
  const int bi = blockIdx.x;
  const int t = threadIdx.x;
  __shared__ float sA[512];
  __shared__ float red[256];
  sA[t] = agg[(size_t)bi * 512 + t];
  sA[t + 256] = agg[(size_t)bi * 512 + t + 256];
  __syncthreads();
  float v0 = 0.f, v1 = 0.f;
#pragma unroll 4
  for (int k = 0; k < 512; ++k) {
    float a = sA[k];
    v0 += a * ldf(Wo, (size_t)k * 512 + t, f);
    v1 += a * ldf(Wo, (size_t)k * 512 + t + 256, f);
  }
  v0 += ldf(Wob, t, f) + nodeF[(size_t)bi * 512 + t];
  v1 += ldf(Wob, t + 256, f) + nodeF[(size_t)bi * 512 + t + 256];
  red[t] = v0 + v1;
  __syncthreads();
  for (int s = 128; s > 0; s >>= 1) {
    if (t < s) red[t] += red[t + s];
    __syncthreads();
  }
  float mean = red[0] * (1.f / 512.f);
  __syncthreads();
  red[t] = (v0 - mean) * (v0 - mean) + (v1 - mean) * (v1 - mean);
  __syncthreads();
  for (int s = 128; s > 0; s >>= 1) {
    if (t < s) red[t] += red[t + s];
    __syncthreads();
  }
  float var = red[0] * (1.f / 512.f);
  float inv = rsqrtf(var + 1e-5f);
  stf(dout, (size_t)bi * 512 + t,
      (v0 - mean) * inv * ldf(lng, t, f) + ldf(lnb, t, f), f);
  stf(dout, (size_t)bi * 512 + t + 256,
      (v1 - mean) * inv * ldf(lng, t + 256, f) + ldf(lnb, t + 256, f), f);
}

extern "C" void kernel_launch(void* const* d_in, const int* in_sizes, int n_in, void* d_out,
                              int out_size, void* d_ws, size_t ws_size, hipStream_t stream) {
  (void)in_sizes; (void)n_in; (void)out_size; (void)ws_size;
  const void* node = d_in[0];
  const void* edge = d_in[1];
  const void* adj = d_in[2];
  const void* Wn_w = d_in[3];
  const void* Wn_b = d_in[4];
  const void* We1_w = d_in[5];
  const void* We1_b = d_in[6];
  const void* We2_w = d_in[7];
  // d_in[8] = We2_b: constant over j -> cancels in softmax, unused.
  const void* Wm_w = d_in[9];
  const void* Wm_b = d_in[10];
  const void* Wu1_w = d_in[11];
  const void* Wu1_b = d_in[12];
  const void* Wu2_w = d_in[13];
  const void* Wu2_b = d_in[14];
  const void* Wo_w = d_in[15];
  const void* Wo_b = d_in[16];
  const void* ln_g = d_in[17];
  const void* ln_b = d_in[18];

  char* w = (char*)d_ws;
  int* flag = (int*)w;       w += 256;
  float* h = (float*)w;      w += 262144 * 4;
  float* P1 = (float*)w;     w += 262144 * 4;
  float* Q1 = (float*)w;     w += 262144 * 4;
  float* P2 = (float*)w;     w += 262144 * 4;
  float* Q2 = (float*)w;     w += 262144 * 4;
  float* msg = (float*)w;    w += 262144 * 4;
  float* logits = (float*)w; w += 524288 * 4;
  float* amean = (float*)w;  w += 65536 * 4;
  float* agg = (float*)w;    w += 262144 * 4;
  float* nodeF = (float*)w;  w += 262144 * 4;
  bfloat* WtA = (bfloat*)w;  w += 262144 * 2;
  bfloat* WtB = (bfloat*)w;  w += 262144 * 2;
  bfloat* WtC = (bfloat*)w;  w += 262144 * 2;

  detect_dtype<<<1, 256, 0, stream>>>((const unsigned short*)node, flag);
  hipMemsetAsync(logits, 0, 524288 * 4, stream);
  cvt_node<<<1024, 256, 0, stream>>>(node, flag, nodeF);
  transpose3<<<3072, 256, 0, stream>>>(We1_w, Wu1_w, Wu2_w, flag, WtA, WtB, WtC);
  small_gemm<<<128, 256, 0, stream>>>(nodeF, Wn_w, 0, Wn_b, flag, h);
  small_gemm<<<128, 256, 0, stream>>>(h, We1_w, 0, We1_b, flag, P1);
  small_gemm<<<128, 256, 0, stream>>>(h, We1_w, 262144, nullptr, flag, Q1);
  small_gemm<<<128, 256, 0, stream>>>(h, Wu1_w, 0, Wu1_b, flag, P2);
  small_gemm<<<128, 256, 0, stream>>>(h, Wu1_w, 262144, nullptr, flag, Q2);
  small_gemm<<<128, 256, 0, stream>>>(h, Wm_w, 0, Wm_b, flag, msg);
  k3_edge_mlp<<<dim3(512, 8), 256, 0, stream>>>(edge, WtA, WtB, P1, Q1, P2, Q2, We2_w, flag,
                                                logits, d_out);
  softmax_mean<<<512, 128, 0, stream>>>(logits, adj, flag, amean);
  aggregate<<<512, 256, 0, stream>>>(amean, msg, agg);
  node_out<<<512, 256, 0, stream>>>(agg, Wo_w, Wo_b, nodeF, ln_g, ln_b, flag, d_out);
  k6_edge_out<<<1024, 512, 0, stream>>>(WtC, Wu2_b, edge, flag, d_out);
}

// Round 4
// 1038.882 us; speedup vs baseline: 1.3954x; 1.3954x over previous
//
#include <hip/hip_runtime.h>
#include <hip/hip_bf16.h>

// GraphConvLayer B=4,N=128,D=512,H=8. Input dtype (bf16|fp32) runtime-detected
// -> flag in ws; output dtype follows input dtype.
// f==1 (fp32): E pre-converted to bf16 into d_out's outE region, block-strided:
//   k6 block bm owns outE rows [bm*64,(bm+1)*64) = bytes [bm*131072,+131072).
//   Within that range: [Ebf16 64 rows x 1024B | u 64 rows x 1024B].
//   k3 reads Ebf16 (A operand) + writes u; k6 reads both from its OWN range,
//   adds residual into acc, __syncthreads(), then overwrites range with fp32 out.
// f==0 (bf16): k3/k6 read E from d_in; u block-strided at dout+524288+bm*65536.
// LDS staging is XOR-swizzled (lane fetches global seg ^ ((row>>1)&3)) so
// ds_read_b128 fragment reads are 2-way (free) instead of 8-way conflicted.
// k3 grid order bm_hi*64 + bn*8 + bm_lo keeps the 8 bn-blocks of one E tile on
// one XCD (blockIdx%8 dispatch) -> E fetched into exactly one L2, once.

typedef __bf16  bf16x8 __attribute__((ext_vector_type(8)));
typedef float   f32x4  __attribute__((ext_vector_type(4)));
typedef __hip_bfloat16 bfloat;

#define AS1 __attribute__((address_space(1)))
#define AS3 __attribute__((address_space(3)))

__device__ __forceinline__ void g2l16(const void* g, void* l) {
  __builtin_amdgcn_global_load_lds((AS1 void*)g, (AS3 void*)l, 16, 0, 0);
}

__device__ __forceinline__ float ldf(const void* p, size_t i, int f) {
  return f ? ((const float*)p)[i] : __bfloat162float(((const bfloat*)p)[i]);
}
__device__ __forceinline__ void stf(void* p, size_t i, float v, int f) {
  if (f) ((float*)p)[i] = v;
  else   ((bfloat*)p)[i] = __float2bfloat16(v);
}

__global__ __launch_bounds__(256) void detect_dtype(const unsigned short* nu, int* flag) {
  __shared__ int bad;
  if (threadIdx.x == 0) bad = 0;
  __syncthreads();
  int local = 0;
  for (int i = threadIdx.x; i < 4096; i += 256) {
    int ex = (nu[i] >> 7) & 0xFF;   // bf16-view exponent; >=0xC0 impossible for real data
    if (ex >= 0xC0) local = 1;
  }
  if (local) atomicOr(&bad, 1);
  __syncthreads();
  if (threadIdx.x == 0) *flag = bad;
}

// f==1 only: E fp32 row-major -> bf16 block-strided into dout outE region
__global__ __launch_bounds__(256) void cvt_edge(const float* E, const int* flag, void* dout) {
  if (*flag == 0) return;
  const size_t i = (size_t)blockIdx.x * 256 + threadIdx.x;  // 4M threads, 8 elems each
  const size_t m = i >> 6;
  const int c8 = (int)(i & 63);
  const float* src = E + m * 512 + (size_t)c8 * 8;
  f32x4 lo = *(const f32x4*)src;
  f32x4 hi = *(const f32x4*)(src + 4);
  bf16x8 v;
  v[0] = (__bf16)lo[0]; v[1] = (__bf16)lo[1]; v[2] = (__bf16)lo[2]; v[3] = (__bf16)lo[3];
  v[4] = (__bf16)hi[0]; v[5] = (__bf16)hi[1]; v[6] = (__bf16)hi[2]; v[7] = (__bf16)hi[3];
  char* eb = (char*)dout + 1048576;
  *(bf16x8*)(eb + (m >> 6) * 131072 + (m & 63) * 1024 + (size_t)c8 * 16) = v;
}

__global__ __launch_bounds__(256) void transpose3(const void* We1, const void* Wu1,
                                                  const void* Wu2, const int* flag,
                                                  bfloat* WtA, bfloat* WtB, bfloat* WtC) {
  const int f = *flag;
  int idx = blockIdx.x * 256 + threadIdx.x;  // 3*2^18
  int m = idx >> 18;
  int r = idx & 262143;
  int n = r >> 9, k = r & 511;
  size_t si = (size_t)k * 512 + n;
  float v;
  bfloat* dst;
  if (m == 0)      { v = ldf(We1, 524288 + si, f); dst = WtA; }
  else if (m == 1) { v = ldf(Wu1, 524288 + si, f); dst = WtB; }
  else             { v = ldf(Wu2, si, f);          dst = WtC; }
  dst[(size_t)n * 512 + k] = __float2bfloat16(v);
}

// generic 512x512x512: A dual-dtype (amode=1 -> fp32 always, else follows flag)
__global__ __launch_bounds__(256) void small_gemm(const void* A, int amode, const void* W,
                                                  size_t woff, const void* bias,
                                                  const int* flag, float* out) {
  const int f = *flag;
  const int af = amode ? 1 : f;
  __shared__ float sA[4][512];
  const int t = threadIdx.x;
  const int r0 = blockIdx.x * 4;
  for (int idx = t; idx < 2048; idx += 256)
    sA[idx >> 9][idx & 511] = ldf(A, (size_t)(r0 + (idx >> 9)) * 512 + (idx & 511), af);
  __syncthreads();
  float acc0[4] = {0.f, 0.f, 0.f, 0.f}, acc1[4] = {0.f, 0.f, 0.f, 0.f};
#pragma unroll 4
  for (int k = 0; k < 512; ++k) {
    float w0 = ldf(W, woff + (size_t)k * 512 + t, f);
    float w1 = ldf(W, woff + (size_t)k * 512 + t + 256, f);
#pragma unroll
    for (int r = 0; r < 4; ++r) {
      acc0[r] += sA[r][k] * w0;
      acc1[r] += sA[r][k] * w1;
    }
  }
  float b0 = bias ? ldf(bias, t, f) : 0.f;
  float b1 = bias ? ldf(bias, t + 256, f) : 0.f;
#pragma unroll
  for (int r = 0; r < 4; ++r) {
    out[(size_t)(r0 + r) * 512 + t] = acc0[r] + b0;
    out[(size_t)(r0 + r) * 512 + t + 256] = acc1[r] + b1;
  }
}

// the 5 h-dependent 512x512x512 GEMMs in one launch (grid 128 x 5)
__global__ __launch_bounds__(256) void fused5(const float* h, const void* We1, const void* We1b,
                                              const void* Wu1, const void* Wu1b, const void* Wm,
                                              const void* Wmb, const int* flag, float* P1,
                                              float* Q1, float* P2, float* Q2, float* msgv) {
  const int f = *flag;
  const void* W;
  size_t woff = 0;
  const void* bias = nullptr;
  float* out;
  switch (blockIdx.y) {
    case 0:  W = We1; bias = We1b; out = P1; break;
    case 1:  W = We1; woff = 262144; out = Q1; break;
    case 2:  W = Wu1; bias = Wu1b; out = P2; break;
    case 3:  W = Wu1; woff = 262144; out = Q2; break;
    default: W = Wm;  bias = Wmb;  out = msgv; break;
  }
  __shared__ float sA[4][512];
  const int t = threadIdx.x;
  const int r0 = blockIdx.x * 4;
  for (int idx = t; idx < 2048; idx += 256)
    sA[idx >> 9][idx & 511] = h[(size_t)(r0 + (idx >> 9)) * 512 + (idx & 511)];
  __syncthreads();
  float acc0[4] = {0.f, 0.f, 0.f, 0.f}, acc1[4] = {0.f, 0.f, 0.f, 0.f};
#pragma unroll 4
  for (int k = 0; k < 512; ++k) {
    float w0 = ldf(W, woff + (size_t)k * 512 + t, f);
    float w1 = ldf(W, woff + (size_t)k * 512 + t + 256, f);
#pragma unroll
    for (int r = 0; r < 4; ++r) {
      acc0[r] += sA[r][k] * w0;
      acc1[r] += sA[r][k] * w1;
    }
  }
  float b0 = bias ? ldf(bias, t, f) : 0.f;
  float b1 = bias ? ldf(bias, t + 256, f) : 0.f;
#pragma unroll
  for (int r = 0; r < 4; ++r) {
    out[(size_t)(r0 + r) * 512 + t] = acc0[r] + b0;
    out[(size_t)(r0 + r) * 512 + t + 256] = acc1[r] + b1;
  }
}

__global__ __launch_bounds__(256) void k3_edge_mlp(const void* E, const bfloat* WtA,
                                                   const bfloat* WtB, const float* P1,
                                                   const float* Q1, const float* P2,
                                                   const float* Q2, const void* We2,
                                                   const int* flag, float* logits, void* dout) {
  const int f = *flag;
  __shared__ __align__(16) char smem[16384];
  char* sA = smem;
  char* sB = smem + 8192;
  f32x4 acc[4][4];
#pragma unroll
  for (int mi = 0; mi < 4; ++mi)
#pragma unroll
    for (int ni = 0; ni < 4; ++ni) acc[mi][ni] = (f32x4){0.f, 0.f, 0.f, 0.f};

  // XCD-locality swizzle: 8 bn-blocks of one bm on one XCD, 8 apart in idx
  const int idx0 = blockIdx.x;                 // 0..4095
  const int bm = (idx0 >> 6) * 8 + (idx0 & 7); // 0..511 == b*128+i
  const int bn = (idx0 >> 3) & 7;              // 0..7: <4 attn, >=4 u
  const bool attn = bn < 4;
  const bfloat* Bg = attn ? WtA + (size_t)bn * 65536 : WtB + (size_t)(bn - 4) * 65536;
  const bfloat* Eb = (const bfloat*)E;
  const char* eb = (const char*)dout + 1048576;  // Ebf16 (f==1)

  const int t = threadIdx.x;
  const int lane = t & 63;
  const int wave = t >> 6;
  const int wrow = wave >> 1, wcol = wave & 1;
  const int l15 = lane & 15;
  const int q = lane >> 4;

  for (int kt = 0; kt < 16; ++kt) {
    __syncthreads();
    const int k0 = kt * 32;
#pragma unroll
    for (int c = 0; c < 2; ++c) {
      const int idx = c * 256 + t;
      const int row = idx >> 2;
      const int gseg = (idx & 3) ^ ((row >> 1) & 3);  // XOR swizzle
      g2l16(Bg + (size_t)row * 512 + k0 + gseg * 8, sB + (c * 256 + wave * 64) * 16);
      const int gr = bm * 128 + row;
      if (f) {
        g2l16(eb + (size_t)(gr >> 6) * 131072 + (size_t)(gr & 63) * 1024 +
                  (size_t)(k0 + gseg * 8) * 2,
              sA + (c * 256 + wave * 64) * 16);
      } else {
        g2l16(Eb + (size_t)gr * 512 + k0 + gseg * 8, sA + (c * 256 + wave * 64) * 16);
      }
    }
    __syncthreads();
    bf16x8 afr[4], bfr[4];
#pragma unroll
    for (int mi = 0; mi < 4; ++mi) {
      const int r = wrow * 64 + mi * 16 + l15;
      afr[mi] = *(const bf16x8*)(sA + ((size_t)r * 32 + (q ^ ((r >> 1) & 3)) * 8) * 2);
    }
#pragma unroll
    for (int ni = 0; ni < 4; ++ni) {
      const int r = wcol * 64 + ni * 16 + l15;
      bfr[ni] = *(const bf16x8*)(sB + ((size_t)r * 32 + (q ^ ((r >> 1) & 3)) * 8) * 2);
    }
#pragma unroll
    for (int mi = 0; mi < 4; ++mi)
#pragma unroll
      for (int ni = 0; ni < 4; ++ni)
        acc[mi][ni] = __builtin_amdgcn_mfma_f32_16x16x32_bf16(afr[mi], bfr[ni], acc[mi][ni], 0, 0, 0);
  }

  const int b = bm >> 7;
  const int colbase = (attn ? bn : (bn - 4)) * 128 + wcol * 64;
  const float* P = attn ? P1 : P2;
  const float* Qm = attn ? Q1 : Q2;

  if (!attn) {
    char* ubase = (char*)dout + (f ? (1048576 + 65536) : 524288);
    const size_t blkstride = f ? 131072 : 65536;
#pragma unroll
    for (int mi = 0; mi < 4; ++mi)
#pragma unroll
      for (int rr = 0; rr < 4; ++rr) {
        const int j = wrow * 64 + mi * 16 + q * 4 + rr;
        const size_t m = (size_t)bm * 128 + j;
        bfloat* urow = (bfloat*)(ubase + (m >> 6) * blkstride + (size_t)(m & 63) * 1024);
#pragma unroll
        for (int ni = 0; ni < 4; ++ni) {
          const int c = colbase + ni * 16 + l15;
          float x = acc[mi][ni][rr] + P[(size_t)bm * 512 + c] + Qm[((size_t)b * 128 + j) * 512 + c];
          float g = 0.5f * x * (1.0f + erff(x * 0.70710678118654752f));
          urow[c] = __float2bfloat16(g);
        }
      }
  } else {
    float w2[4][8];
#pragma unroll
    for (int ni = 0; ni < 4; ++ni) {
      const int c = colbase + ni * 16 + l15;
#pragma unroll
      for (int hh = 0; hh < 8; ++hh) w2[ni][hh] = ldf(We2, (size_t)c * 8 + hh, f);
    }
#pragma unroll
    for (int mi = 0; mi < 4; ++mi)
#pragma unroll
      for (int rr = 0; rr < 4; ++rr) {
        const int j = wrow * 64 + mi * 16 + q * 4 + rr;
        float e[4];
#pragma unroll
        for (int ni = 0; ni < 4; ++ni) {
          const int c = colbase + ni * 16 + l15;
          float x = acc[mi][ni][rr] + P[(size_t)bm * 512 + c] + Qm[((size_t)b * 128 + j) * 512 + c];
          e[ni] = (x >= 0.f) ? x : 0.2f * x;
        }
        float part[8];
#pragma unroll
        for (int hh = 0; hh < 8; ++hh) {
          float s = e[0] * w2[0][hh] + e[1] * w2[1][hh] + e[2] * w2[2][hh] + e[3] * w2[3][hh];
          s += __shfl_xor(s, 1);
          s += __shfl_xor(s, 2);
          s += __shfl_xor(s, 4);
          s += __shfl_xor(s, 8);
          part[hh] = s;
        }
        if (l15 == 0) {
          float* lp = logits + ((size_t)bm * 128 + j) * 8;
#pragma unroll
          for (int hh = 0; hh < 8; ++hh) atomicAdd(lp + hh, part[hh]);
        }
      }
  }
}

__global__ __launch_bounds__(512) void k6_edge_out(const bfloat* WtC, const void* Wu2b,
                                                   const void* E, const int* flag, void* dout) {
  const int f = *flag;
  __shared__ __align__(16) char smem[36864];
  char* sA = smem;          // 64 rows x 64B
  char* sB = smem + 4096;   // 512 rows x 64B
  f32x4 acc[2][8];
#pragma unroll
  for (int mi = 0; mi < 2; ++mi)
#pragma unroll
    for (int ni = 0; ni < 8; ++ni) acc[mi][ni] = (f32x4){0.f, 0.f, 0.f, 0.f};

  const int bm = blockIdx.x;  // 0..1023, owns outE rows [bm*64,(bm+1)*64)
  const int t = threadIdx.x;  // 8 waves
  const int lane = t & 63;
  const int wave = t >> 6;
  const int wm = wave >> 2, wn = wave & 3;
  const int l15 = lane & 15;
  const int q = lane >> 4;
  const size_t r0 = (size_t)bm * 64;
  const char* ua = (const char*)dout +
                   (f ? (1048576 + (size_t)bm * 131072 + 65536) : (524288 + (size_t)bm * 65536));

  for (int kt = 0; kt < 16; ++kt) {
    __syncthreads();
    const int k0 = kt * 32;
    if (t < 256) {
      const int row = t >> 2;
      const int gseg = (t & 3) ^ ((row >> 1) & 3);
      g2l16(ua + (size_t)row * 1024 + (size_t)(k0 + gseg * 8) * 2, sA + wave * 64 * 16);
    }
#pragma unroll
    for (int c = 0; c < 4; ++c) {
      const int idx = c * 512 + t;
      const int row = idx >> 2;
      const int gseg = (idx & 3) ^ ((row >> 1) & 3);
      g2l16(WtC + (size_t)row * 512 + k0 + gseg * 8, sB + (c * 512 + wave * 64) * 16);
    }
    __syncthreads();
    bf16x8 afr[2], bfr[8];
#pragma unroll
    for (int mi = 0; mi < 2; ++mi) {
      const int r = wm * 32 + mi * 16 + l15;
      afr[mi] = *(const bf16x8*)(sA + ((size_t)r * 32 + (q ^ ((r >> 1) & 3)) * 8) * 2);
    }
#pragma unroll
    for (int ni = 0; ni < 8; ++ni) {
      const int r = wn * 128 + ni * 16 + l15;
      bfr[ni] = *(const bf16x8*)(sB + ((size_t)r * 32 + (q ^ ((r >> 1) & 3)) * 8) * 2);
    }
#pragma unroll
    for (int mi = 0; mi < 2; ++mi)
#pragma unroll
      for (int ni = 0; ni < 8; ++ni)
        acc[mi][ni] = __builtin_amdgcn_mfma_f32_16x16x32_bf16(afr[mi], bfr[ni], acc[mi][ni], 0, 0, 0);
  }
  // add bias + residual into acc (all reads BEFORE the barrier; in-place range)
  const bfloat* eres = (const bfloat*)((const char*)dout + 1048576 + (size_t)bm * 131072);
#pragma unroll
  for (int mi = 0; mi < 2; ++mi)
#pragma unroll
    for (int rr = 0; rr < 4; ++rr) {
      const int j = wm * 32 + mi * 16 + q * 4 + rr;
#pragma unroll
      for (int ni = 0; ni < 8; ++ni) {
        const int c = wn * 128 + ni * 16 + l15;
        float r = f ? __bfloat162float(eres[(size_t)j * 512 + c])
                    : __bfloat162float(((const bfloat*)E)[(r0 + j) * 512 + c]);
        acc[mi][ni][rr] += ldf(Wu2b, c, f) + r;
      }
    }
  __syncthreads();  // all residual reads done before any store overwrites the range
#pragma unroll
  for (int mi = 0; mi < 2; ++mi)
#pragma unroll
    for (int rr = 0; rr < 4; ++rr) {
      const int j = wm * 32 + mi * 16 + q * 4 + rr;
      const size_t row = r0 + j;
#pragma unroll
      for (int ni = 0; ni < 8; ++ni) {
        const int c = wn * 128 + ni * 16 + l15;
        stf(dout, 262144 + row * 512 + c, acc[mi][ni][rr], f);
      }
    }
}

__global__ __launch_bounds__(128) void softmax_mean(const float* logits, const void* adj,
                                                    const int* flag, float* amean) {
  const int f = *flag;
  const int bi = blockIdx.x;
  const int j = threadIdx.x;
  __shared__ float red[128];
  float macc = 0.f;
  for (int hh = 0; hh < 8; ++hh) {
    float x = logits[((size_t)bi * 128 + j) * 8 + hh];
    red[j] = x;
    __syncthreads();
    for (int s = 64; s > 0; s >>= 1) {
      if (j < s) red[j] = fmaxf(red[j], red[j + s]);
      __syncthreads();
    }
    float mx = red[0];
    __syncthreads();
    float ex = expf(x - mx);
    red[j] = ex;
    __syncthreads();
    for (int s = 64; s > 0; s >>= 1) {
      if (j < s) red[j] += red[j + s];
      __syncthreads();
    }
    float sum = red[0];
    __syncthreads();
    macc += ex / sum;
  }
  amean[(size_t)bi * 128 + j] = macc * 0.125f * ldf(adj, (size_t)bi * 128 + j, f);
}

// fused aggregate + Wo-gemm + LayerNorm (block bi)
__global__ __launch_bounds__(256) void node_fused(const float* amean, const float* msg,
                                                  const void* Wo, const void* Wob,
                                                  const void* node, const void* lng,
                                                  const void* lnb, const int* flag, void* dout) {
  const int f = *flag;
  const int bi = blockIdx.x;
  const int b = bi >> 7;
  const int t = threadIdx.x;
  __shared__ float am[128];
  __shared__ float sAgg[512];
  __shared__ float red[256];
  if (t < 128) am[t] = amean[(size_t)bi * 128 + t];
  __syncthreads();
  float a0 = 0.f, a1 = 0.f;
#pragma unroll 4
  for (int jj = 0; jj < 128; ++jj) {
    const float* mr = msg + ((size_t)b * 128 + jj) * 512;
    a0 += am[jj] * mr[t];
    a1 += am[jj] * mr[t + 256];
  }
  sAgg[t] = a0;
  sAgg[t + 256] = a1;
  __syncthreads();
  float v0 = 0.f, v1 = 0.f;
#pragma unroll 4
  for (int k = 0; k < 512; ++k) {
    float a = sAgg[k];
    v0 += a * ldf(Wo, (size_t)k * 512 + t, f);
    v1 += a * ldf(Wo, (size_t)k * 512 + t + 256, f);
  }
  v0 += ldf(Wob, t, f) + ldf(node, (size_t)bi * 512 + t, f);
  v1 += ldf(Wob, t + 256, f) + ldf(node, (size_t)bi * 512 + t + 256, f);
  red[t] = v0 + v1;
  __syncthreads();
  for (int s = 128; s > 0; s >>= 1) {
    if (t < s) red[t] += red[t + s];
    __syncthreads();
  }
  float mean = red[0] * (1.f / 512.f);
  __syncthreads();
  red[t] = (v0 - mean) * (v0 - mean) + (v1 - mean) * (v1 - mean);
  __syncthreads();
  for (int s = 128; s > 0; s >>= 1) {
    if (t < s) red[t] += red[t + s];
    __syncthreads();
  }
  float var = red[0] * (1.f / 512.f);
  float inv = rsqrtf(var + 1e-5f);
  stf(dout, (size_t)bi * 512 + t, (v0 - mean) * inv * ldf(lng, t, f) + ldf(lnb, t, f), f);
  stf(dout, (size_t)bi * 512 + t + 256,
      (v1 - mean) * inv * ldf(lng, t + 256, f) + ldf(lnb, t + 256, f), f);
}

extern "C" void kernel_launch(void* const* d_in, const int* in_sizes, int n_in, void* d_out,
                              int out_size, void* d_ws, size_t ws_size, hipStream_t stream) {
  (void)in_sizes; (void)n_in; (void)out_size; (void)ws_size;
  const void* node = d_in[0];
  const void* edge = d_in[1];
  const void* adj = d_in[2];
  const void* Wn_w = d_in[3];
  const void* Wn_b = d_in[4];
  const void* We1_w = d_in[5];
  const void* We1_b = d_in[6];
  const void* We2_w = d_in[7];
  // d_in[8] = We2_b: constant over j -> cancels in softmax, unused.
  const void* Wm_w = d_in[9];
  const void* Wm_b = d_in[10];
  const void* Wu1_w = d_in[11];
  const void* Wu1_b = d_in[12];
  const void* Wu2_w = d_in[13];
  const void* Wu2_b = d_in[14];
  const void* Wo_w = d_in[15];
  const void* Wo_b = d_in[16];
  const void* ln_g = d_in[17];
  const void* ln_b = d_in[18];

  char* w = (char*)d_ws;
  int* flag = (int*)w;       w += 256;
  float* h = (float*)w;      w += 262144 * 4;
  float* P1 = (float*)w;     w += 262144 * 4;
  float* Q1 = (float*)w;     w += 262144 * 4;
  float* P2 = (float*)w;     w += 262144 * 4;
  float* Q2 = (float*)w;     w += 262144 * 4;
  float* msg = (float*)w;    w += 262144 * 4;
  float* logits = (float*)w; w += 524288 * 4;
  float* amean = (float*)w;  w += 65536 * 4;
  bfloat* WtA = (bfloat*)w;  w += 262144 * 2;
  bfloat* WtB = (bfloat*)w;  w += 262144 * 2;
  bfloat* WtC = (bfloat*)w;  w += 262144 * 2;

  detect_dtype<<<1, 256, 0, stream>>>((const unsigned short*)node, flag);
  hipMemsetAsync(logits, 0, 524288 * 4, stream);
  cvt_edge<<<16384, 256, 0, stream>>>((const float*)edge, flag, d_out);
  transpose3<<<3072, 256, 0, stream>>>(We1_w, Wu1_w, Wu2_w, flag, WtA, WtB, WtC);
  small_gemm<<<128, 256, 0, stream>>>(node, 0, Wn_w, 0, Wn_b, flag, h);
  fused5<<<dim3(128, 5), 256, 0, stream>>>(h, We1_w, We1_b, Wu1_w, Wu1_b, Wm_w, Wm_b, flag,
                                           P1, Q1, P2, Q2, msg);
  k3_edge_mlp<<<4096, 256, 0, stream>>>(edge, WtA, WtB, P1, Q1, P2, Q2, We2_w, flag,
                                        logits, d_out);
  softmax_mean<<<512, 128, 0, stream>>>(logits, adj, flag, amean);
  node_fused<<<512, 256, 0, stream>>>(amean, msg, Wo_w, Wo_b, node, ln_g, ln_b, flag, d_out);
  k6_edge_out<<<1024, 512, 0, stream>>>(WtC, Wu2_b, edge, flag, d_out);
}

// Round 5
// 878.276 us; speedup vs baseline: 1.6506x; 1.1829x over previous
//
#include <hip/hip_runtime.h>
#include <hip/hip_bf16.h>

// GraphConvLayer B=4,N=128,D=512,H=8. Input dtype (bf16|fp32) runtime-detected
// -> flag in ws; output dtype follows input dtype.
// f==1: E pre-converted to bf16 into d_out's outE region, chunk-layout:
//   chunk c (64 rows) occupies bytes [1048576 + c*131072, +131072):
//   [Ebf16 64x1024B | u 64x1024B]. outE fp32 rows of chunk c = same byte range;
//   k6 block owns one chunk: reads Ebf16+u, barrier, overwrites with fp32 out.
// f==0: E read from d_in (bf16); u chunks at dout+524288+c*65536.
// XCD-locality chain: cvt_edge, k3, k6 grids swizzled so chunk c is written and
// read on XCD (c>>1)&7 (k3 block bm -> XCD bm&7; its chunks are 2bm,2bm+1).
// LDS XOR-swizzled staging (0 bank conflicts, verified r4). BK=64 (8 iters).
// u-epilogue goes through LDS -> 16B/lane coalesced global stores.
// Attn logits: smem-combined per block, plain stores to 4-slot partials (no atomics).

typedef __bf16  bf16x8 __attribute__((ext_vector_type(8)));
typedef float   f32x4  __attribute__((ext_vector_type(4)));
typedef __hip_bfloat16 bfloat;

#define AS1 __attribute__((address_space(1)))
#define AS3 __attribute__((address_space(3)))

__device__ __forceinline__ void g2l16(const void* g, void* l) {
  __builtin_amdgcn_global_load_lds((AS1 void*)g, (AS3 void*)l, 16, 0, 0);
}

__device__ __forceinline__ float ldf(const void* p, size_t i, int f) {
  return f ? ((const float*)p)[i] : __bfloat162float(((const bfloat*)p)[i]);
}
__device__ __forceinline__ void stf(void* p, size_t i, float v, int f) {
  if (f) ((float*)p)[i] = v;
  else   ((bfloat*)p)[i] = __float2bfloat16(v);
}

// tanh-form GELU (max abs err ~3e-4 vs exact erf form; well under threshold)
__device__ __forceinline__ float gelu_f(float x) {
  float y = 0.7978845608028654f * (x + 0.044715f * x * x * x);
  float e = __expf(2.0f * y);
  float t = 1.0f - 2.0f / (e + 1.0f);
  return 0.5f * x * (1.0f + t);
}

__global__ __launch_bounds__(256) void detect_dtype(const unsigned short* nu, int* flag) {
  __shared__ int bad;
  if (threadIdx.x == 0) bad = 0;
  __syncthreads();
  int local = 0;
  for (int i = threadIdx.x; i < 4096; i += 256) {
    int ex = (nu[i] >> 7) & 0xFF;
    if (ex >= 0xC0) local = 1;
  }
  if (local) atomicOr(&bad, 1);
  __syncthreads();
  if (threadIdx.x == 0) *flag = bad;
}

// f==1 only: E fp32 -> bf16 chunk layout in dout. Grid 16384, XCD-aligned:
// chunk c handled by blocks with blockIdx%8 == (c>>1)&7.
__global__ __launch_bounds__(256) void cvt_edge(const float* E, const int* flag, void* dout) {
  if (*flag == 0) return;
  const int e = blockIdx.x & 7;
  const int x = blockIdx.x >> 3;          // 0..2047
  const int m = x >> 5;                   // 0..63
  const int h = (x >> 4) & 1;
  const int s = x & 15;                   // 16 blocks per chunk
  const int c = 2 * e + 16 * m + h;       // chunk 0..1023
  const int t = threadIdx.x;
  const int rloc = s * 4 + (t >> 6);      // row within chunk 0..63
  const int c8 = t & 63;
  const float* src = E + ((size_t)c * 64 + rloc) * 512 + (size_t)c8 * 8;
  f32x4 lo = *(const f32x4*)src;
  f32x4 hi = *(const f32x4*)(src + 4);
  bf16x8 v;
  v[0] = (__bf16)lo[0]; v[1] = (__bf16)lo[1]; v[2] = (__bf16)lo[2]; v[3] = (__bf16)lo[3];
  v[4] = (__bf16)hi[0]; v[5] = (__bf16)hi[1]; v[6] = (__bf16)hi[2]; v[7] = (__bf16)hi[3];
  char* eb = (char*)dout + 1048576;
  *(bf16x8*)(eb + (size_t)c * 131072 + (size_t)rloc * 1024 + (size_t)c8 * 16) = v;
}

__global__ __launch_bounds__(256) void transpose3(const void* We1, const void* Wu1,
                                                  const void* Wu2, const int* flag,
                                                  bfloat* WtA, bfloat* WtB, bfloat* WtC) {
  const int f = *flag;
  int idx = blockIdx.x * 256 + threadIdx.x;
  int m = idx >> 18;
  int r = idx & 262143;
  int n = r >> 9, k = r & 511;
  size_t si = (size_t)k * 512 + n;
  float v;
  bfloat* dst;
  if (m == 0)      { v = ldf(We1, 524288 + si, f); dst = WtA; }
  else if (m == 1) { v = ldf(Wu1, 524288 + si, f); dst = WtB; }
  else             { v = ldf(Wu2, si, f);          dst = WtC; }
  dst[(size_t)n * 512 + k] = __float2bfloat16(v);
}

__global__ __launch_bounds__(256) void small_gemm(const void* A, int amode, const void* W,
                                                  size_t woff, const void* bias,
                                                  const int* flag, float* out) {
  const int f = *flag;
  const int af = amode ? 1 : f;
  __shared__ float sA[4][512];
  const int t = threadIdx.x;
  const int r0 = blockIdx.x * 4;
  for (int idx = t; idx < 2048; idx += 256)
    sA[idx >> 9][idx & 511] = ldf(A, (size_t)(r0 + (idx >> 9)) * 512 + (idx & 511), af);
  __syncthreads();
  float acc0[4] = {0.f, 0.f, 0.f, 0.f}, acc1[4] = {0.f, 0.f, 0.f, 0.f};
#pragma unroll 4
  for (int k = 0; k < 512; ++k) {
    float w0 = ldf(W, woff + (size_t)k * 512 + t, f);
    float w1 = ldf(W, woff + (size_t)k * 512 + t + 256, f);
#pragma unroll
    for (int r = 0; r < 4; ++r) {
      acc0[r] += sA[r][k] * w0;
      acc1[r] += sA[r][k] * w1;
    }
  }
  float b0 = bias ? ldf(bias, t, f) : 0.f;
  float b1 = bias ? ldf(bias, t + 256, f) : 0.f;
#pragma unroll
  for (int r = 0; r < 4; ++r) {
    out[(size_t)(r0 + r) * 512 + t] = acc0[r] + b0;
    out[(size_t)(r0 + r) * 512 + t + 256] = acc1[r] + b1;
  }
}

// 5 h-dependent 512^3 GEMMs in one launch
__global__ __launch_bounds__(256) void fused5(const float* h, const void* We1, const void* We1b,
                                              const void* Wu1, const void* Wu1b, const void* Wm,
                                              const void* Wmb, const int* flag, float* P1,
                                              float* Q1, float* P2, float* Q2, float* msgv) {
  const int f = *flag;
  const void* W;
  size_t woff = 0;
  const void* bias = nullptr;
  float* out;
  switch (blockIdx.y) {
    case 0:  W = We1; bias = We1b; out = P1; break;
    case 1:  W = We1; woff = 262144; out = Q1; break;
    case 2:  W = Wu1; bias = Wu1b; out = P2; break;
    case 3:  W = Wu1; woff = 262144; out = Q2; break;
    default: W = Wm;  bias = Wmb;  out = msgv; break;
  }
  __shared__ float sA[4][512];
  const int t = threadIdx.x;
  const int r0 = blockIdx.x * 4;
  for (int idx = t; idx < 2048; idx += 256)
    sA[idx >> 9][idx & 511] = h[(size_t)(r0 + (idx >> 9)) * 512 + (idx & 511)];
  __syncthreads();
  float acc0[4] = {0.f, 0.f, 0.f, 0.f}, acc1[4] = {0.f, 0.f, 0.f, 0.f};
#pragma unroll 4
  for (int k = 0; k < 512; ++k) {
    float w0 = ldf(W, woff + (size_t)k * 512 + t, f);
    float w1 = ldf(W, woff + (size_t)k * 512 + t + 256, f);
#pragma unroll
    for (int r = 0; r < 4; ++r) {
      acc0[r] += sA[r][k] * w0;
      acc1[r] += sA[r][k] * w1;
    }
  }
  float b0 = bias ? ldf(bias, t, f) : 0.f;
  float b1 = bias ? ldf(bias, t + 256, f) : 0.f;
#pragma unroll
  for (int r = 0; r < 4; ++r) {
    out[(size_t)(r0 + r) * 512 + t] = acc0[r] + b0;
    out[(size_t)(r0 + r) * 512 + t + 256] = acc1[r] + b1;
  }
}

// K3: 128x128 tile, BK=64, 8 K-iters. LDS: sA 16KB + sB 16KB (reused by epilogues).
__global__ __launch_bounds__(256) void k3_edge_mlp(const void* E, const bfloat* WtA,
                                                   const bfloat* WtB, const float* P1,
                                                   const float* Q1, const float* P2,
                                                   const float* Q2, const void* We2,
                                                   const int* flag, float* logits4, void* dout) {
  const int f = *flag;
  __shared__ __align__(16) char smem[32768];
  char* sA = smem;
  char* sB = smem + 16384;
  f32x4 acc[4][4];
#pragma unroll
  for (int mi = 0; mi < 4; ++mi)
#pragma unroll
    for (int ni = 0; ni < 4; ++ni) acc[mi][ni] = (f32x4){0.f, 0.f, 0.f, 0.f};

  const int idx0 = blockIdx.x;                 // 0..4095
  const int bm = (idx0 >> 6) * 8 + (idx0 & 7); // XCD = bm&7
  const int bn = (idx0 >> 3) & 7;              // <4 attn, >=4 u
  const bool attn = bn < 4;
  const bfloat* Bg = attn ? WtA + (size_t)bn * 65536 : WtB + (size_t)(bn - 4) * 65536;
  const bfloat* Eb = (const bfloat*)E;
  const char* eb = (const char*)dout + 1048576;

  const int t = threadIdx.x;
  const int lane = t & 63;
  const int wave = t >> 6;
  const int wrow = wave >> 1, wcol = wave & 1;
  const int l15 = lane & 15;
  const int q = lane >> 4;

  for (int kt = 0; kt < 8; ++kt) {
    __syncthreads();
    const int k0 = kt * 64;
    // stage 128 rows x 64 k (8 chunks of 16B per row), XOR-swizzled: phys p holds g = p^(row&7)
#pragma unroll
    for (int c = 0; c < 4; ++c) {
      const int L = c * 256 + t;                 // 0..1023
      const int row = L >> 3;
      const int g = (L & 7) ^ ((row >> 0) & 7);
      char* dstb = sB + (c * 256 + wave * 64) * 16;
      char* dsta = sA + (c * 256 + wave * 64) * 16;
      g2l16(Bg + (size_t)row * 512 + k0 + g * 8, dstb);
      const int gr = bm * 128 + row;
      if (f) {
        g2l16(eb + (size_t)(gr >> 6) * 131072 + (size_t)(gr & 63) * 1024 +
                  (size_t)(k0 + g * 8) * 2,
              dsta);
      } else {
        g2l16(Eb + (size_t)gr * 512 + k0 + g * 8, dsta);
      }
    }
    __syncthreads();
#pragma unroll
    for (int kk = 0; kk < 2; ++kk) {
      bf16x8 afr[4], bfr[4];
#pragma unroll
      for (int mi = 0; mi < 4; ++mi) {
        const int r = wrow * 64 + mi * 16 + l15;
        afr[mi] = *(const bf16x8*)(sA + (size_t)r * 128 + (((kk * 4 + q) ^ (r & 7)) * 16));
      }
#pragma unroll
      for (int ni = 0; ni < 4; ++ni) {
        const int r = wcol * 64 + ni * 16 + l15;
        bfr[ni] = *(const bf16x8*)(sB + (size_t)r * 128 + (((kk * 4 + q) ^ (r & 7)) * 16));
      }
#pragma unroll
      for (int mi = 0; mi < 4; ++mi)
#pragma unroll
        for (int ni = 0; ni < 4; ++ni)
          acc[mi][ni] =
              __builtin_amdgcn_mfma_f32_16x16x32_bf16(afr[mi], bfr[ni], acc[mi][ni], 0, 0, 0);
    }
  }

  const int b = bm >> 7;
  const int blockcol = (attn ? bn : (bn - 4)) * 128;
  const float* P = attn ? P1 : P2;
  const float* Qm = attn ? Q1 : Q2;
  // hoisted P (row-constant per block): global col = blockcol + wcol*64 + ni*16 + l15
  float pv[4];
#pragma unroll
  for (int ni = 0; ni < 4; ++ni)
    pv[ni] = P[(size_t)bm * 512 + blockcol + wcol * 64 + ni * 16 + l15];

  if (!attn) {
    __syncthreads();  // K-loop frag reads done; reuse smem as 128x128 bf16 image
    // write phase: val(j, cc) at j*256 + ((cc>>3)^(j&15))*16 + (cc&7)*2
    bfloat* simg = (bfloat*)smem;
#pragma unroll
    for (int mi = 0; mi < 4; ++mi)
#pragma unroll
      for (int rr = 0; rr < 4; ++rr) {
        const int j = wrow * 64 + mi * 16 + q * 4 + rr;
#pragma unroll
        for (int ni = 0; ni < 4; ++ni) {
          const int cc = wcol * 64 + ni * 16 + l15;
          const int c = blockcol + cc;
          float x = acc[mi][ni][rr] + pv[ni] + Qm[((size_t)b * 128 + j) * 512 + c];
          *(bfloat*)(smem + (size_t)j * 256 + (((cc >> 3) ^ (j & 15)) * 16) + (cc & 7) * 2) =
              __float2bfloat16(gelu_f(x));
        }
      }
    (void)simg;
    __syncthreads();
    // read phase: 16B/lane, lanes 0..15 cover one full 256B local row -> coalesced
    char* ubase = (char*)dout + (f ? (1048576 + 65536) : 524288);
    const size_t blkstride = f ? 131072 : 65536;
#pragma unroll
    for (int rd = 0; rd < 8; ++rd) {
      const int j = rd * 16 + (t >> 4);
      const int ch = t & 15;
      f32x4 v = *(const f32x4*)(smem + (size_t)j * 256 + ((ch ^ (j & 15)) * 16));
      const size_t m = (size_t)bm * 128 + j;
      *(f32x4*)(ubase + (m >> 6) * blkstride + (m & 63) * 1024 + (size_t)blockcol * 2 +
                (size_t)ch * 16) = v;
    }
  } else {
    float w2[4][8];
#pragma unroll
    for (int ni = 0; ni < 4; ++ni) {
      const int c = blockcol + wcol * 64 + ni * 16 + l15;
#pragma unroll
      for (int hh = 0; hh < 8; ++hh) w2[ni][hh] = ldf(We2, (size_t)c * 8 + hh, f);
    }
    __syncthreads();  // reuse smem: partial[wcol][j][h] floats (2*128*8*4 = 8KB)
    float* sp = (float*)smem;
#pragma unroll
    for (int mi = 0; mi < 4; ++mi)
#pragma unroll
      for (int rr = 0; rr < 4; ++rr) {
        const int j = wrow * 64 + mi * 16 + q * 4 + rr;
        float e4[4];
#pragma unroll
        for (int ni = 0; ni < 4; ++ni) {
          const int c = blockcol + wcol * 64 + ni * 16 + l15;
          float x = acc[mi][ni][rr] + pv[ni] + Qm[((size_t)b * 128 + j) * 512 + c];
          e4[ni] = (x >= 0.f) ? x : 0.2f * x;
        }
#pragma unroll
        for (int hh = 0; hh < 8; ++hh) {
          float s = e4[0] * w2[0][hh] + e4[1] * w2[1][hh] + e4[2] * w2[2][hh] + e4[3] * w2[3][hh];
          s += __shfl_xor(s, 1);
          s += __shfl_xor(s, 2);
          s += __shfl_xor(s, 4);
          s += __shfl_xor(s, 8);
          if (l15 == 0) sp[(wcol * 128 + j) * 8 + hh] = s;
        }
      }
    __syncthreads();
    // combine wcol halves + store: thread t -> j = t>>1, 4 h's (16B contiguous)
    {
      const int j = t >> 1;
      const int h0 = (t & 1) * 4;
      f32x4 v;
#pragma unroll
      for (int k = 0; k < 4; ++k)
        v[k] = sp[j * 8 + h0 + k] + sp[(128 + j) * 8 + h0 + k];
      *(f32x4*)(logits4 + (((size_t)bn * 512 + bm) * 128 + j) * 8 + h0) = v;
    }
  }
}

// K6: out = E + u@Wu2 + b. One block owns one 64-row chunk; BK=32 (36KB LDS).
// Grid swizzled so chunk c runs on XCD (c>>1)&7 (where k3 wrote u & Ebf16).
__global__ __launch_bounds__(512) void k6_edge_out(const bfloat* WtC, const void* Wu2b,
                                                   const void* E, const int* flag, void* dout) {
  const int f = *flag;
  __shared__ __align__(16) char smem[36864];
  char* sA = smem;          // 64 rows x 64B
  char* sB = smem + 4096;   // 512 rows x 64B
  f32x4 acc[2][8];
#pragma unroll
  for (int mi = 0; mi < 2; ++mi)
#pragma unroll
    for (int ni = 0; ni < 8; ++ni) acc[mi][ni] = (f32x4){0.f, 0.f, 0.f, 0.f};

  const int e = blockIdx.x & 7;
  const int x = blockIdx.x >> 3;
  const int bm = 2 * e + 16 * (x >> 1) + (x & 1);  // chunk 0..1023, XCD = (bm>>1)&7 == e
  const int t = threadIdx.x;
  const int lane = t & 63;
  const int wave = t >> 6;
  const int wm = wave >> 2, wn = wave & 3;
  const int l15 = lane & 15;
  const int q = lane >> 4;
  const size_t r0 = (size_t)bm * 64;
  const char* ua = (const char*)dout +
                   (f ? (1048576 + (size_t)bm * 131072 + 65536) : (524288 + (size_t)bm * 65536));

  for (int kt = 0; kt < 16; ++kt) {
    __syncthreads();
    const int k0 = kt * 32;
    if (t < 256) {
      const int row = t >> 2;
      const int gseg = (t & 3) ^ ((row >> 1) & 3);
      g2l16(ua + (size_t)row * 1024 + (size_t)(k0 + gseg * 8) * 2, sA + wave * 64 * 16);
    }
#pragma unroll
    for (int c = 0; c < 4; ++c) {
      const int idx = c * 512 + t;
      const int row = idx >> 2;
      const int gseg = (idx & 3) ^ ((row >> 1) & 3);
      g2l16(WtC + (size_t)row * 512 + k0 + gseg * 8, sB + (c * 512 + wave * 64) * 16);
    }
    __syncthreads();
    bf16x8 afr[2], bfr[8];
#pragma unroll
    for (int mi = 0; mi < 2; ++mi) {
      const int r = wm * 32 + mi * 16 + l15;
      afr[mi] = *(const bf16x8*)(sA + ((size_t)r * 32 + (q ^ ((r >> 1) & 3)) * 8) * 2);
    }
#pragma unroll
    for (int ni = 0; ni < 8; ++ni) {
      const int r = wn * 128 + ni * 16 + l15;
      bfr[ni] = *(const bf16x8*)(sB + ((size_t)r * 32 + (q ^ ((r >> 1) & 3)) * 8) * 2);
    }
#pragma unroll
    for (int mi = 0; mi < 2; ++mi)
#pragma unroll
      for (int ni = 0; ni < 8; ++ni)
        acc[mi][ni] = __builtin_amdgcn_mfma_f32_16x16x32_bf16(afr[mi], bfr[ni], acc[mi][ni], 0, 0, 0);
  }
  // hoisted bias
  float wb[8];
#pragma unroll
  for (int ni = 0; ni < 8; ++ni) wb[ni] = ldf(Wu2b, wn * 128 + ni * 16 + l15, f);
  // residual reads (before barrier; this block's own byte range)
  const bfloat* eres = (const bfloat*)((const char*)dout + 1048576 + (size_t)bm * 131072);
#pragma unroll
  for (int mi = 0; mi < 2; ++mi)
#pragma unroll
    for (int rr = 0; rr < 4; ++rr) {
      const int j = wm * 32 + mi * 16 + q * 4 + rr;
#pragma unroll
      for (int ni = 0; ni < 8; ++ni) {
        const int c = wn * 128 + ni * 16 + l15;
        float r = f ? __bfloat162float(eres[(size_t)j * 512 + c])
                    : __bfloat162float(((const bfloat*)E)[(r0 + j) * 512 + c]);
        acc[mi][ni][rr] += wb[ni] + r;
      }
    }
  __syncthreads();  // all residual reads drained before overwriting the range
#pragma unroll
  for (int mi = 0; mi < 2; ++mi)
#pragma unroll
    for (int rr = 0; rr < 4; ++rr) {
      const int j = wm * 32 + mi * 16 + q * 4 + rr;
      const size_t row = r0 + j;
#pragma unroll
      for (int ni = 0; ni < 8; ++ni) {
        const int c = wn * 128 + ni * 16 + l15;
        stf(dout, 262144 + row * 512 + c, acc[mi][ni][rr], f);
      }
    }
}

__global__ __launch_bounds__(128) void softmax_mean(const float* logits4, const void* adj,
                                                    const int* flag, float* amean) {
  const int f = *flag;
  const int bi = blockIdx.x;
  const int j = threadIdx.x;
  __shared__ float red[128];
  float macc = 0.f;
  for (int hh = 0; hh < 8; ++hh) {
    float x = 0.f;
#pragma unroll
    for (int s = 0; s < 4; ++s)
      x += logits4[(((size_t)s * 512 + bi) * 128 + j) * 8 + hh];
    red[j] = x;
    __syncthreads();
    for (int s = 64; s > 0; s >>= 1) {
      if (j < s) red[j] = fmaxf(red[j], red[j + s]);
      __syncthreads();
    }
    float mx = red[0];
    __syncthreads();
    float ex = __expf(x - mx);
    red[j] = ex;
    __syncthreads();
    for (int s = 64; s > 0; s >>= 1) {
      if (j < s) red[j] += red[j + s];
      __syncthreads();
    }
    float sum = red[0];
    __syncthreads();
    macc += ex / sum;
  }
  amean[(size_t)bi * 128 + j] = macc * 0.125f * ldf(adj, (size_t)bi * 128 + j, f);
}

// fused aggregate + Wo + LayerNorm
__global__ __launch_bounds__(256) void node_fused(const float* amean, const float* msg,
                                                  const void* Wo, const void* Wob,
                                                  const void* node, const void* lng,
                                                  const void* lnb, const int* flag, void* dout) {
  const int f = *flag;
  const int bi = blockIdx.x;
  const int b = bi >> 7;
  const int t = threadIdx.x;
  __shared__ float am[128];
  __shared__ float sAgg[512];
  __shared__ float red[256];
  if (t < 128) am[t] = amean[(size_t)bi * 128 + t];
  __syncthreads();
  float a0 = 0.f, a1 = 0.f;
#pragma unroll 4
  for (int jj = 0; jj < 128; ++jj) {
    const float* mr = msg + ((size_t)b * 128 + jj) * 512;
    a0 += am[jj] * mr[t];
    a1 += am[jj] * mr[t + 256];
  }
  sAgg[t] = a0;
  sAgg[t + 256] = a1;
  __syncthreads();
  float v0 = 0.f, v1 = 0.f;
#pragma unroll 4
  for (int k = 0; k < 512; ++k) {
    float a = sAgg[k];
    v0 += a * ldf(Wo, (size_t)k * 512 + t, f);
    v1 += a * ldf(Wo, (size_t)k * 512 + t + 256, f);
  }
  v0 += ldf(Wob, t, f) + ldf(node, (size_t)bi * 512 + t, f);
  v1 += ldf(Wob, t + 256, f) + ldf(node, (size_t)bi * 512 + t + 256, f);
  red[t] = v0 + v1;
  __syncthreads();
  for (int s = 128; s > 0; s >>= 1) {
    if (t < s) red[t] += red[t + s];
    __syncthreads();
  }
  float mean = red[0] * (1.f / 512.f);
  __syncthreads();
  red[t] = (v0 - mean) * (v0 - mean) + (v1 - mean) * (v1 - mean);
  __syncthreads();
  for (int s = 128; s > 0; s >>= 1) {
    if (t < s) red[t] += red[t + s];
    __syncthreads();
  }
  float var = red[0] * (1.f / 512.f);
  float inv = rsqrtf(var + 1e-5f);
  stf(dout, (size_t)bi * 512 + t, (v0 - mean) * inv * ldf(lng, t, f) + ldf(lnb, t, f), f);
  stf(dout, (size_t)bi * 512 + t + 256,
      (v1 - mean) * inv * ldf(lng, t + 256, f) + ldf(lnb, t + 256, f), f);
}

extern "C" void kernel_launch(void* const* d_in, const int* in_sizes, int n_in, void* d_out,
                              int out_size, void* d_ws, size_t ws_size, hipStream_t stream) {
  (void)in_sizes; (void)n_in; (void)out_size; (void)ws_size;
  const void* node = d_in[0];
  const void* edge = d_in[1];
  const void* adj = d_in[2];
  const void* Wn_w = d_in[3];
  const void* Wn_b = d_in[4];
  const void* We1_w = d_in[5];
  const void* We1_b = d_in[6];
  const void* We2_w = d_in[7];
  // d_in[8] = We2_b: constant over j -> cancels in softmax, unused.
  const void* Wm_w = d_in[9];
  const void* Wm_b = d_in[10];
  const void* Wu1_w = d_in[11];
  const void* Wu1_b = d_in[12];
  const void* Wu2_w = d_in[13];
  const void* Wu2_b = d_in[14];
  const void* Wo_w = d_in[15];
  const void* Wo_b = d_in[16];
  const void* ln_g = d_in[17];
  const void* ln_b = d_in[18];

  char* w = (char*)d_ws;
  int* flag = (int*)w;        w += 256;
  float* h = (float*)w;       w += 262144 * 4;
  float* P1 = (float*)w;      w += 262144 * 4;
  float* Q1 = (float*)w;      w += 262144 * 4;
  float* P2 = (float*)w;      w += 262144 * 4;
  float* Q2 = (float*)w;      w += 262144 * 4;
  float* msg = (float*)w;     w += 262144 * 4;
  float* logits4 = (float*)w; w += (size_t)4 * 524288 * 4;  // [4][512][128][8] fp32 = 8MB
  float* amean = (float*)w;   w += 65536 * 4;
  bfloat* WtA = (bfloat*)w;   w += 262144 * 2;
  bfloat* WtB = (bfloat*)w;   w += 262144 * 2;
  bfloat* WtC = (bfloat*)w;   w += 262144 * 2;
  // total ~15.3MB

  detect_dtype<<<1, 256, 0, stream>>>((const unsigned short*)node, flag);
  cvt_edge<<<16384, 256, 0, stream>>>((const float*)edge, flag, d_out);
  transpose3<<<3072, 256, 0, stream>>>(We1_w, Wu1_w, Wu2_w, flag, WtA, WtB, WtC);
  small_gemm<<<128, 256, 0, stream>>>(node, 0, Wn_w, 0, Wn_b, flag, h);
  fused5<<<dim3(128, 5), 256, 0, stream>>>(h, We1_w, We1_b, Wu1_w, Wu1_b, Wm_w, Wm_b, flag,
                                           P1, Q1, P2, Q2, msg);
  k3_edge_mlp<<<4096, 256, 0, stream>>>(edge, WtA, WtB, P1, Q1, P2, Q2, We2_w, flag,
                                        logits4, d_out);
  softmax_mean<<<512, 128, 0, stream>>>(logits4, adj, flag, amean);
  node_fused<<<512, 256, 0, stream>>>(amean, msg, Wo_w, Wo_b, node, ln_g, ln_b, flag, d_out);
  k6_edge_out<<<1024, 512, 0, stream>>>(WtC, Wu2_b, edge, flag, d_out);
}